// Round 1
// baseline (20311.101 us; speedup 1.0000x reference)
//
#include <hip/hip_runtime.h>
#include <hip/hip_bf16.h>
#include <hip/hip_cooperative_groups.h>
#include <cstddef>

namespace cg = cooperative_groups;

typedef short bf16x8 __attribute__((ext_vector_type(8)));
typedef float f32x4 __attribute__((ext_vector_type(4)));

#define T_STEPS 512
#define BATCH   64
#define DIM     1024   // I == H == 1024
#define BD      (BATCH*DIM)      // 65536
#define XB_ELEMS ((size_t)T_STEPS*BATCH*DIM)  // 33554432

__device__ __forceinline__ float sigmoidf_(float x) {
    return 1.f / (1.f + __expf(-x));
}
__device__ __forceinline__ float tanhf_(float x) {
    // 2*sigmoid(2x)-1 : no NaN at extremes
    return 2.f / (1.f + __expf(-2.f * x)) - 1.f;
}
__device__ __forceinline__ unsigned short f2bf(float f) {
    union { float f; unsigned int u; } v; v.f = f;
    unsigned int u = v.u + 0x7fffu + ((v.u >> 16) & 1u);  // RNE
    return (unsigned short)(u >> 16);
}

// Grid: 256 blocks x 256 threads. Blocks 0..127 -> layer 0, 128..255 -> layer 1.
// Each block owns 8 hidden units (32 gate rows), weights resident in LDS (bf16).
__global__ void __launch_bounds__(256, 1)
lstm_fused(const float* __restrict__ x,
           const float* __restrict__ hx,
           const float* __restrict__ cx,
           const float* __restrict__ w_ih0, const float* __restrict__ w_hh0,
           const float* __restrict__ b_ih0, const float* __restrict__ b_hh0,
           const float* __restrict__ w_ih1, const float* __restrict__ w_hh1,
           const float* __restrict__ b_ih1, const float* __restrict__ b_hh1,
           float* __restrict__ out,
           unsigned short* __restrict__ ws)
{
    // ws layout (bf16 elems): xb[T][B][DIM], h0[2][BD], h1[2][BD]
    unsigned short* xb = ws;
    unsigned short* h0 = ws + XB_ELEMS;
    unsigned short* h1 = h0 + 2 * BD;

    const int tid   = threadIdx.x;
    const int lane  = tid & 63;
    const int wave  = tid >> 6;
    const int bid   = blockIdx.x;
    const int layer = bid >> 7;
    const int ib    = bid & 127;
    const int hb    = ib * 8;          // first hidden unit owned by this block

    // 2 matrices x 32 gate rows x (1024 + 8 pad) bf16  = 132 KB
    __shared__ __align__(16) unsigned short wlds[2][32][1032];

    // ---- stage weight slices into LDS as bf16 (one-time) ----
    {
        const float* wsrc0 = layer ? w_ih1 : w_ih0;
        const float* wsrc1 = layer ? w_hh1 : w_hh0;
        for (int m = 0; m < 2; ++m) {
            const float* wm = m ? wsrc1 : wsrc0;
            for (int i = tid; i < 8192; i += 256) {     // 32*1024/4 float4s
                int rr = i >> 8;                        // 0..31 (LDS row)
                int k4 = (i & 255) * 4;                 // 0..1020
                int q  = rr >> 3, u = rr & 7;           // gate, unit
                const float4 v = *(const float4*)(wm + (size_t)(q*DIM + hb + u)*DIM + k4);
                ushort4 o;
                o.x = f2bf(v.x); o.y = f2bf(v.y); o.z = f2bf(v.z); o.w = f2bf(v.w);
                *(ushort4*)(&wlds[m][rr][k4]) = o;
            }
        }
    }

    // ---- cast x to bf16 into ws (grid-stride) ----
    {
        const int nthr = 256 * gridDim.x;
        const int gtid = bid * 256 + tid;
        const float4* xv = (const float4*)x;
        const int n4 = (int)(XB_ELEMS / 4);
        for (int i = gtid; i < n4; i += nthr) {
            float4 v = xv[i];
            ushort4 o;
            o.x = f2bf(v.x); o.y = f2bf(v.y); o.z = f2bf(v.z); o.w = f2bf(v.w);
            *(ushort4*)(xb + (size_t)i * 4) = o;
        }
    }

    // ---- init h ping-pong slot [1] from hx (used when (t-1)&1 == 1, i.e. t=0) ----
    {
        unsigned short* hdst = (layer ? h1 : h0) + BD;
        const float* hsrc = hx + (size_t)layer * BD;
        for (int e = tid; e < 512; e += 256) {
            int row = e >> 3, u = e & 7;
            hdst[row*DIM + hb + u] = f2bf(hsrc[row*DIM + hb + u]);
        }
    }

    const int col  = lane & 15;      // MFMA col within N-tile
    const int quad = lane >> 4;      // 0..3
    const bool lo  = col < 8;
    const int u    = lane & 7;       // hidden-unit offset for lo lanes

    // biases (per-lane, constant over time)
    const float* bi = layer ? b_ih1 : b_ih0;
    const float* bh = layer ? b_hh1 : b_hh0;
    const int r0 = (col < 8) ? (0*DIM + hb + col) : (1*DIM + hb + col - 8); // i|f
    const int r1 = (col < 8) ? (2*DIM + hb + col) : (3*DIM + hb + col - 8); // g|o
    const float bias0 = bi[r0] + bh[r0];
    const float bias1 = bi[r1] + bh[r1];

    // c-state in registers (lo lanes own 4 batch rows each)
    float creg[4];
    {
        const float* csrc = cx + (size_t)layer * BD;
        #pragma unroll
        for (int r = 0; r < 4; ++r) {
            int m = wave*16 + quad*4 + r;
            creg[r] = lo ? csrc[m*DIM + hb + u] : 0.f;
        }
    }

    cg::grid_group grid = cg::this_grid();
    __syncthreads();
    grid.sync();   // xb + h init visible everywhere

    const int arow = wave*16 + col;  // A-fragment row (batch index)

    for (int k = 0; k <= T_STEPS; ++k) {
        const int t = layer ? (k - 1) : k;
        const bool active = layer ? (k >= 1) : (k < T_STEPS);
        if (active) {
            const unsigned short* A1 = layer ? (h0 + (size_t)(t & 1) * BD)
                                             : (xb + (size_t)t * BD);
            const unsigned short* A2 = (layer ? h1 : h0) + (size_t)((t - 1) & 1) * BD;

            f32x4 acc0 = {0.f, 0.f, 0.f, 0.f};
            f32x4 acc1 = {0.f, 0.f, 0.f, 0.f};

            #pragma unroll 1
            for (int g = 0; g < 2; ++g) {
                const unsigned short* Ap = g ? A2 : A1;
                const unsigned short* Abase = Ap + (size_t)arow * DIM + quad * 8;
                #pragma unroll 8
                for (int k0 = 0; k0 < DIM; k0 += 32) {
                    bf16x8 a  = *(const bf16x8*)(Abase + k0);
                    bf16x8 b0 = *(const bf16x8*)(&wlds[g][col][k0 + quad*8]);
                    bf16x8 b1 = *(const bf16x8*)(&wlds[g][16 + col][k0 + quad*8]);
                    acc0 = __builtin_amdgcn_mfma_f32_16x16x32_bf16(a, b0, acc0, 0, 0, 0);
                    acc1 = __builtin_amdgcn_mfma_f32_16x16x32_bf16(a, b1, acc1, 0, 0, 0);
                }
            }

            unsigned short* hout = (layer ? h1 : h0) + (size_t)(t & 1) * BD;
            #pragma unroll
            for (int r = 0; r < 4; ++r) {
                float pre0 = acc0[r] + bias0;          // i (lo) | f (hi)
                float pre1 = acc1[r] + bias1;          // g (lo) | o (hi)
                float alt0 = __shfl_xor(pre0, 8);
                float alt1 = __shfl_xor(pre1, 8);
                if (lo) {
                    float ig = sigmoidf_(pre0);
                    float fg = sigmoidf_(alt0);
                    float gg = tanhf_(pre1);
                    float og = sigmoidf_(alt1);
                    float c  = fg * creg[r] + ig * gg;
                    creg[r]  = c;
                    float h  = og * tanhf_(c);
                    int m = wave*16 + quad*4 + r;
                    hout[m*DIM + hb + u] = f2bf(h);
                    if (layer) {
                        out[(size_t)t * BD + m*DIM + hb + u] = h;
                        if (t == T_STEPS - 1) {
                            out[(size_t)T_STEPS*BD + 1*BD + m*DIM + hb + u] = h;  // hn[1]
                            out[(size_t)T_STEPS*BD + 3*BD + m*DIM + hb + u] = c;  // cn[1]
                        }
                    } else if (t == T_STEPS - 1) {
                        out[(size_t)T_STEPS*BD + 0*BD + m*DIM + hb + u] = h;      // hn[0]
                        out[(size_t)T_STEPS*BD + 2*BD + m*DIM + hb + u] = c;      // cn[0]
                    }
                }
            }
        }
        grid.sync();
    }
}

extern "C" void kernel_launch(void* const* d_in, const int* in_sizes, int n_in,
                              void* d_out, int out_size, void* d_ws, size_t ws_size,
                              hipStream_t stream) {
    const float* x     = (const float*)d_in[0];
    const float* hx    = (const float*)d_in[1];
    const float* cx    = (const float*)d_in[2];
    const float* w_ih0 = (const float*)d_in[3];
    const float* w_hh0 = (const float*)d_in[4];
    const float* b_ih0 = (const float*)d_in[5];
    const float* b_hh0 = (const float*)d_in[6];
    const float* w_ih1 = (const float*)d_in[7];
    const float* w_hh1 = (const float*)d_in[8];
    const float* b_ih1 = (const float*)d_in[9];
    const float* b_hh1 = (const float*)d_in[10];
    float* outp = (float*)d_out;
    unsigned short* wsp = (unsigned short*)d_ws;

    void* args[] = { &x, &hx, &cx, &w_ih0, &w_hh0, &b_ih0, &b_hh0,
                     &w_ih1, &w_hh1, &b_ih1, &b_hh1, &outp, &wsp };
    hipLaunchCooperativeKernel((void*)lstm_fused, dim3(256), dim3(256),
                               args, 0, stream);
}

// Round 2
// 16810.913 us; speedup vs baseline: 1.2082x; 1.2082x over previous
//
#include <hip/hip_runtime.h>
#include <hip/hip_bf16.h>
#include <hip/hip_cooperative_groups.h>
#include <cstddef>

namespace cg = cooperative_groups;

typedef short bf16x8 __attribute__((ext_vector_type(8)));
typedef float f32x4 __attribute__((ext_vector_type(4)));

#define T_STEPS 512
#define BATCH   64
#define DIM     1024   // I == H == 1024
#define BD      (BATCH*DIM)      // 65536
#define XB_ELEMS ((size_t)T_STEPS*BATCH*DIM)  // 33554432

__device__ __forceinline__ float sigmoidf_(float x) {
    return 1.f / (1.f + __expf(-x));
}
__device__ __forceinline__ float tanhf_(float x) {
    return 2.f / (1.f + __expf(-2.f * x)) - 1.f;
}
__device__ __forceinline__ unsigned short f2bf(float f) {
    union { float f; unsigned int u; } v; v.f = f;
    unsigned int u = v.u + 0x7fffu + ((v.u >> 16) & 1u);  // RNE
    return (unsigned short)(u >> 16);
}

// Lightweight device-scope barrier primitives (monotonic counters, no reset).
__device__ __forceinline__ void bar_arrive(unsigned* c) {
    __syncthreads();   // all block stores vmcnt-retired into L2 before signal
    if (threadIdx.x == 0)
        __hip_atomic_fetch_add(c, 1u, __ATOMIC_RELEASE, __HIP_MEMORY_SCOPE_AGENT);
}
__device__ __forceinline__ void bar_wait(unsigned* c, unsigned target) {
    if (threadIdx.x == 0) {
        while (__hip_atomic_load(c, __ATOMIC_ACQUIRE, __HIP_MEMORY_SCOPE_AGENT) < target) {
            __builtin_amdgcn_s_sleep(1);
        }
    }
    __syncthreads();
    __builtin_amdgcn_fence(__ATOMIC_ACQUIRE, "agent");
}

// Grid: 256 blocks x 256 threads. Blocks 0..127 -> layer 0, 128..255 -> layer 1.
// Each block owns 8 hidden units (32 gate rows), weights resident in LDS (bf16).
__global__ void __launch_bounds__(256, 1)
lstm_fused(const float* __restrict__ x,
           const float* __restrict__ hx,
           const float* __restrict__ cx,
           const float* __restrict__ w_ih0, const float* __restrict__ w_hh0,
           const float* __restrict__ b_ih0, const float* __restrict__ b_hh0,
           const float* __restrict__ w_ih1, const float* __restrict__ w_hh1,
           const float* __restrict__ b_ih1, const float* __restrict__ b_hh1,
           float* __restrict__ out,
           unsigned short* __restrict__ ws)
{
    // ws layout (bf16 elems): xb[T][B][DIM], h0[2][BD], h1[2][BD], counters
    unsigned short* xb = ws;
    unsigned short* h0 = ws + XB_ELEMS;
    unsigned short* h1 = h0 + 2 * BD;
    unsigned* ctr = (unsigned*)(h1 + 2 * BD);   // ctr[0]=layer0, ctr[32]=layer1

    const int tid   = threadIdx.x;
    const int lane  = tid & 63;
    const int wave  = tid >> 6;
    const int bid   = blockIdx.x;
    const int layer = bid >> 7;
    const int ib    = bid & 127;
    const int hb    = ib * 8;          // first hidden unit owned by this block

    // 2 matrices x 32 gate rows x (1024 + 8 pad) bf16  = 132 KB
    __shared__ __align__(16) unsigned short wlds[2][32][1032];

    // ---- stage weight slices into LDS as bf16 (one-time) ----
    {
        const float* wsrc0 = layer ? w_ih1 : w_ih0;
        const float* wsrc1 = layer ? w_hh1 : w_hh0;
        for (int m = 0; m < 2; ++m) {
            const float* wm = m ? wsrc1 : wsrc0;
            for (int i = tid; i < 8192; i += 256) {     // 32*1024/4 float4s
                int rr = i >> 8;                        // 0..31 (LDS row)
                int k4 = (i & 255) * 4;                 // 0..1020
                int q  = rr >> 3, u = rr & 7;           // gate, unit
                const float4 v = *(const float4*)(wm + (size_t)(q*DIM + hb + u)*DIM + k4);
                ushort4 o;
                o.x = f2bf(v.x); o.y = f2bf(v.y); o.z = f2bf(v.z); o.w = f2bf(v.w);
                *(ushort4*)(&wlds[m][rr][k4]) = o;
            }
        }
    }

    // ---- cast x to bf16 into ws (grid-stride) ----
    {
        const int nthr = 256 * gridDim.x;
        const int gtid = bid * 256 + tid;
        const float4* xv = (const float4*)x;
        const int n4 = (int)(XB_ELEMS / 4);
        for (int i = gtid; i < n4; i += nthr) {
            float4 v = xv[i];
            ushort4 o;
            o.x = f2bf(v.x); o.y = f2bf(v.y); o.z = f2bf(v.z); o.w = f2bf(v.w);
            *(ushort4*)(xb + (size_t)i * 4) = o;
        }
    }

    // ---- init h ping-pong slot [1] from hx (used at t=0: (t-1)&1 == 1) ----
    {
        unsigned short* hdst = (layer ? h1 : h0) + BD;
        const float* hsrc = hx + (size_t)layer * BD;
        for (int e = tid; e < 512; e += 256) {
            int row = e >> 3, u = e & 7;
            hdst[row*DIM + hb + u] = f2bf(hsrc[row*DIM + hb + u]);
        }
    }

    // ---- zero the step counters (re-done every launch; deterministic) ----
    if (bid == 0 && tid == 0) {
        __hip_atomic_store(&ctr[0], 0u, __ATOMIC_RELAXED, __HIP_MEMORY_SCOPE_AGENT);
        __hip_atomic_store(&ctr[32], 0u, __ATOMIC_RELAXED, __HIP_MEMORY_SCOPE_AGENT);
    }

    const int col  = lane & 15;      // MFMA col within N-tile
    const int quad = lane >> 4;      // 0..3
    const bool lo  = col < 8;
    const int u    = lane & 7;       // hidden-unit offset for lo lanes

    // biases (per-lane, constant over time)
    const float* bi = layer ? b_ih1 : b_ih0;
    const float* bh = layer ? b_hh1 : b_hh0;
    const int r0 = (col < 8) ? (0*DIM + hb + col) : (1*DIM + hb + col - 8); // i|f
    const int r1 = (col < 8) ? (2*DIM + hb + col) : (3*DIM + hb + col - 8); // g|o
    const float bias0 = bi[r0] + bh[r0];
    const float bias1 = bi[r1] + bh[r1];

    // c-state in registers (lo lanes own 4 batch rows each)
    float creg[4];
    {
        const float* csrc = cx + (size_t)layer * BD;
        #pragma unroll
        for (int r = 0; r < 4; ++r) {
            int m = wave*16 + quad*4 + r;
            creg[r] = lo ? csrc[m*DIM + hb + u] : 0.f;
        }
    }

    cg::grid_group grid = cg::this_grid();
    __syncthreads();
    grid.sync();   // xb, h init, zeroed counters visible everywhere

    const int arow = wave*16 + col;  // A-fragment row (batch index)
    unsigned* c0 = &ctr[0];
    unsigned* c1 = &ctr[32];

    auto do_gemm = [&](const unsigned short* Ap, int g, f32x4& a0v, f32x4& a1v) {
        const unsigned short* Abase = Ap + (size_t)arow * DIM + quad * 8;
        #pragma unroll 8
        for (int k0 = 0; k0 < DIM; k0 += 32) {
            bf16x8 a  = *(const bf16x8*)(Abase + k0);
            bf16x8 b0 = *(const bf16x8*)(&wlds[g][col][k0 + quad*8]);
            bf16x8 b1 = *(const bf16x8*)(&wlds[g][16 + col][k0 + quad*8]);
            a0v = __builtin_amdgcn_mfma_f32_16x16x32_bf16(a, b0, a0v, 0, 0, 0);
            a1v = __builtin_amdgcn_mfma_f32_16x16x32_bf16(a, b1, a1v, 0, 0, 0);
        }
    };

    for (int t = 0; t < T_STEPS; ++t) {
        f32x4 acc0 = {0.f, 0.f, 0.f, 0.f};
        f32x4 acc1 = {0.f, 0.f, 0.f, 0.f};

        if (!layer) {
            // input GEMM on static xb[t] — overlaps peers finishing step t-1
            do_gemm(xb + (size_t)t * BD, 0, acc0, acc1);
            bar_wait(c0, 128u * (unsigned)t);              // peers' h0[t-1] ready
            do_gemm(h0 + (size_t)((t - 1) & 1) * BD, 1, acc0, acc1);
            if (t >= 2) bar_wait(c1, 128u * (unsigned)(t - 1));  // layer1 done reading slot
        } else {
            bar_wait(c1, 128u * (unsigned)t);              // own h1[t-1] ready + slot free
            do_gemm(h1 + (size_t)((t - 1) & 1) * BD, 1, acc0, acc1);
            bar_wait(c0, 128u * (unsigned)(t + 1));        // layer0's h0[t] ready
            do_gemm(h0 + (size_t)(t & 1) * BD, 0, acc0, acc1);
        }

        unsigned short* hout = (layer ? h1 : h0) + (size_t)(t & 1) * BD;
        #pragma unroll
        for (int r = 0; r < 4; ++r) {
            float pre0 = acc0[r] + bias0;          // i (lo) | f (hi)
            float pre1 = acc1[r] + bias1;          // g (lo) | o (hi)
            float alt0 = __shfl_xor(pre0, 8);
            float alt1 = __shfl_xor(pre1, 8);
            if (lo) {
                float ig = sigmoidf_(pre0);
                float fg = sigmoidf_(alt0);
                float gg = tanhf_(pre1);
                float og = sigmoidf_(alt1);
                float c  = fg * creg[r] + ig * gg;
                creg[r]  = c;
                float h  = og * tanhf_(c);
                int m = wave*16 + quad*4 + r;
                hout[m*DIM + hb + u] = f2bf(h);
                if (layer) {
                    out[(size_t)t * BD + m*DIM + hb + u] = h;
                    if (t == T_STEPS - 1) {
                        out[(size_t)T_STEPS*BD + 1*BD + m*DIM + hb + u] = h;  // hn[1]
                        out[(size_t)T_STEPS*BD + 3*BD + m*DIM + hb + u] = c;  // cn[1]
                    }
                } else if (t == T_STEPS - 1) {
                    out[(size_t)T_STEPS*BD + 0*BD + m*DIM + hb + u] = h;      // hn[0]
                    out[(size_t)T_STEPS*BD + 2*BD + m*DIM + hb + u] = c;      // cn[0]
                }
            }
        }

        bar_arrive(layer ? c1 : c0);
    }
}

extern "C" void kernel_launch(void* const* d_in, const int* in_sizes, int n_in,
                              void* d_out, int out_size, void* d_ws, size_t ws_size,
                              hipStream_t stream) {
    const float* x     = (const float*)d_in[0];
    const float* hx    = (const float*)d_in[1];
    const float* cx    = (const float*)d_in[2];
    const float* w_ih0 = (const float*)d_in[3];
    const float* w_hh0 = (const float*)d_in[4];
    const float* b_ih0 = (const float*)d_in[5];
    const float* b_hh0 = (const float*)d_in[6];
    const float* w_ih1 = (const float*)d_in[7];
    const float* w_hh1 = (const float*)d_in[8];
    const float* b_ih1 = (const float*)d_in[9];
    const float* b_hh1 = (const float*)d_in[10];
    float* outp = (float*)d_out;
    unsigned short* wsp = (unsigned short*)d_ws;

    void* args[] = { &x, &hx, &cx, &w_ih0, &w_hh0, &b_ih0, &b_hh0,
                     &w_ih1, &w_hh1, &b_ih1, &b_hh1, &outp, &wsp };
    hipLaunchCooperativeKernel((void*)lstm_fused, dim3(256), dim3(256),
                               args, 0, stream);
}

// Round 3
// 15362.827 us; speedup vs baseline: 1.3221x; 1.0943x over previous
//
#include <hip/hip_runtime.h>
#include <hip/hip_bf16.h>
#include <hip/hip_cooperative_groups.h>
#include <cstddef>

namespace cg = cooperative_groups;

typedef short bf16x8 __attribute__((ext_vector_type(8)));
typedef float f32x4 __attribute__((ext_vector_type(4)));

#define T_STEPS 512
#define BATCH   64
#define DIM     1024   // I == H == 1024
#define BD      (BATCH*DIM)      // 65536
#define XB_ELEMS ((size_t)T_STEPS*BATCH*DIM)  // 33554432
#define FLAG_STRIDE 16           // uints -> 64B between flags (own cache line)

__device__ __forceinline__ float sigmoidf_(float x) {
    return 1.f / (1.f + __expf(-x));
}
__device__ __forceinline__ float tanhf_(float x) {
    return 2.f / (1.f + __expf(-2.f * x)) - 1.f;
}
__device__ __forceinline__ unsigned short f2bf(float f) {
    union { float f; unsigned int u; } v; v.f = f;
    unsigned int u = v.u + 0x7fffu + ((v.u >> 16) & 1u);  // RNE
    return (unsigned short)(u >> 16);
}

// ---- distributed flag barrier: store-only arrive, parallel poll wait ----
__device__ __forceinline__ void bar_arrive(unsigned* myflag, unsigned val) {
    __syncthreads();   // all block stores retired to L2 before signal
    if (threadIdx.x == 0)
        __hip_atomic_store(myflag, val, __ATOMIC_RELEASE, __HIP_MEMORY_SCOPE_AGENT);
}
__device__ __forceinline__ void bar_wait_all(unsigned* flags, unsigned target) {
    // 128 producer flags, one per polling thread -> parallel, no contention
    if (threadIdx.x < 128) {
        unsigned* f = flags + threadIdx.x * FLAG_STRIDE;
        while (__hip_atomic_load(f, __ATOMIC_RELAXED, __HIP_MEMORY_SCOPE_AGENT) < target)
            __builtin_amdgcn_s_sleep(1);
    }
    __syncthreads();
    __builtin_amdgcn_fence(__ATOMIC_ACQUIRE, "agent");
}

// Grid: 256 blocks x 256 threads. Blocks 0..127 -> layer 0, 128..255 -> layer 1.
// Each block owns 8 hidden units (32 gate rows); weights LDS-resident in MFMA
// fragment order (conflict-free lane-linear ds_read_b128).
__global__ void __launch_bounds__(256, 1)
lstm_fused(const float* __restrict__ x,
           const float* __restrict__ hx,
           const float* __restrict__ cx,
           const float* __restrict__ w_ih0, const float* __restrict__ w_hh0,
           const float* __restrict__ b_ih0, const float* __restrict__ b_hh0,
           const float* __restrict__ w_ih1, const float* __restrict__ w_hh1,
           const float* __restrict__ b_ih1, const float* __restrict__ b_hh1,
           float* __restrict__ out,
           unsigned short* __restrict__ ws)
{
    // ws layout (bf16 elems): xb[T][B][DIM], h0[2][BD], h1[2][BD], flags
    unsigned short* xb = ws;
    unsigned short* h0 = ws + XB_ELEMS;
    unsigned short* h1 = h0 + 2 * BD;
    unsigned* flag0 = (unsigned*)(h1 + 2 * BD);        // [128 * FLAG_STRIDE]
    unsigned* flag1 = flag0 + 128 * FLAG_STRIDE;       // [128 * FLAG_STRIDE]

    const int tid   = threadIdx.x;
    const int lane  = tid & 63;
    const int wave  = tid >> 6;
    const int bid   = blockIdx.x;
    const int layer = bid >> 7;
    const int ib    = bid & 127;
    const int hb    = ib * 8;          // first hidden unit owned by this block

    // B operand in MFMA fragment order: [g(2)][ntile(2)][kchunk(32)][lane(64)][8]
    // = 65536 bf16 = 128 KB; wave read is base + lane*16B -> conflict-free.
    __shared__ __align__(16) unsigned short wB[65536];

    // ---- stage weight slices into LDS (one-time), fragment layout ----
    {
        const float* wsrcI = layer ? w_ih1 : w_ih0;
        const float* wsrcH = layer ? w_hh1 : w_hh0;
        for (int idx = tid; idx < 8192; idx += 256) {   // 8192 fragments of 8
            int l  = idx & 63;
            int kc = (idx >> 6) & 31;
            int n  = (idx >> 11) & 1;
            int g  = idx >> 12;
            int c  = l & 15, kq = l >> 4;
            int gate = n * 2 + (c >> 3);                // 0:i 1:f 2:g 3:o
            const float* wm = g ? wsrcH : wsrcI;
            const float* src = wm + (size_t)(gate * DIM + hb + (c & 7)) * DIM + kc * 32 + kq * 8;
            float4 v0 = *(const float4*)(src);
            float4 v1 = *(const float4*)(src + 4);
            unsigned short o[8];
            o[0] = f2bf(v0.x); o[1] = f2bf(v0.y); o[2] = f2bf(v0.z); o[3] = f2bf(v0.w);
            o[4] = f2bf(v1.x); o[5] = f2bf(v1.y); o[6] = f2bf(v1.z); o[7] = f2bf(v1.w);
            *(bf16x8*)(&wB[(size_t)idx * 8]) = *(const bf16x8*)o;
        }
    }

    // ---- cast x to bf16 into ws (grid-stride) ----
    {
        const int nthr = 256 * gridDim.x;
        const int gtid = bid * 256 + tid;
        const float4* xv = (const float4*)x;
        const int n4 = (int)(XB_ELEMS / 4);
        for (int i = gtid; i < n4; i += nthr) {
            float4 v = xv[i];
            ushort4 o;
            o.x = f2bf(v.x); o.y = f2bf(v.y); o.z = f2bf(v.z); o.w = f2bf(v.w);
            *(ushort4*)(xb + (size_t)i * 4) = o;
        }
    }

    // ---- init h ping-pong slot [1] from hx (used at t=0: (t-1)&1 == 1) ----
    {
        unsigned short* hdst = (layer ? h1 : h0) + BD;
        const float* hsrc = hx + (size_t)layer * BD;
        for (int e = tid; e < 512; e += 256) {
            int row = e >> 3, u = e & 7;
            hdst[row * DIM + hb + u] = f2bf(hsrc[row * DIM + hb + u]);
        }
    }

    // ---- zero own flag (every launch; deterministic under graph replay) ----
    if (tid == 0) {
        unsigned* f = (layer ? flag1 : flag0) + ib * FLAG_STRIDE;
        __hip_atomic_store(f, 0u, __ATOMIC_RELAXED, __HIP_MEMORY_SCOPE_AGENT);
    }

    const int col  = lane & 15;      // MFMA col within N-tile
    const int quad = lane >> 4;      // 0..3
    const bool lo  = col < 8;
    const int u    = lane & 7;       // hidden-unit offset for lo lanes

    // biases (per-lane, constant over time)
    const float* bi = layer ? b_ih1 : b_ih0;
    const float* bh = layer ? b_hh1 : b_hh0;
    const int r0 = (col < 8) ? (0 * DIM + hb + col) : (1 * DIM + hb + col - 8); // i|f
    const int r1 = (col < 8) ? (2 * DIM + hb + col) : (3 * DIM + hb + col - 8); // g|o
    const float bias0 = bi[r0] + bh[r0];
    const float bias1 = bi[r1] + bh[r1];

    // c-state in registers (lo lanes own 4 batch rows each)
    float creg[4];
    {
        const float* csrc = cx + (size_t)layer * BD;
        #pragma unroll
        for (int r = 0; r < 4; ++r) {
            int m = wave * 16 + quad * 4 + r;
            creg[r] = lo ? csrc[m * DIM + hb + u] : 0.f;
        }
    }

    cg::grid_group grid = cg::this_grid();
    __syncthreads();
    grid.sync();   // xb, h init, zeroed flags visible everywhere

    const int arow = wave * 16 + col;  // A-fragment row (batch index)

    auto do_gemm = [&](const unsigned short* Ap, int g, f32x4& a0v, f32x4& a1v) {
        const unsigned short* Abase = Ap + (size_t)arow * DIM + quad * 8;
        const unsigned short* B0 = &wB[(size_t)((g * 2 + 0) * 32) * 512 + lane * 8];
        const unsigned short* B1 = &wB[(size_t)((g * 2 + 1) * 32) * 512 + lane * 8];
        #pragma unroll 8
        for (int kc = 0; kc < 32; ++kc) {
            bf16x8 a  = *(const bf16x8*)(Abase + kc * 32);
            bf16x8 b0 = *(const bf16x8*)(B0 + (size_t)kc * 512);
            bf16x8 b1 = *(const bf16x8*)(B1 + (size_t)kc * 512);
            a0v = __builtin_amdgcn_mfma_f32_16x16x32_bf16(a, b0, a0v, 0, 0, 0);
            a1v = __builtin_amdgcn_mfma_f32_16x16x32_bf16(a, b1, a1v, 0, 0, 0);
        }
    };

    unsigned* myflag = (layer ? flag1 : flag0) + ib * FLAG_STRIDE;

    for (int t = 0; t < T_STEPS; ++t) {
        f32x4 acc0 = {0.f, 0.f, 0.f, 0.f};
        f32x4 acc1 = {0.f, 0.f, 0.f, 0.f};

        if (!layer) {
            // input GEMM on static xb[t] — overlaps peers finishing step t-1
            do_gemm(xb + (size_t)t * BD, 0, acc0, acc1);
            bar_wait_all(flag0, (unsigned)t);                 // peers' h0[t-1] ready
            do_gemm(h0 + (size_t)((t - 1) & 1) * BD, 1, acc0, acc1);
            if (t >= 2) bar_wait_all(flag1, (unsigned)(t - 1)); // layer1 done reading slot
        } else {
            bar_wait_all(flag1, (unsigned)t);                 // peers' h1[t-1] ready + slot free
            do_gemm(h1 + (size_t)((t - 1) & 1) * BD, 1, acc0, acc1);
            bar_wait_all(flag0, (unsigned)(t + 1));           // layer0's h0[t] ready
            do_gemm(h0 + (size_t)(t & 1) * BD, 0, acc0, acc1);
        }

        unsigned short* hout = (layer ? h1 : h0) + (size_t)(t & 1) * BD;
        #pragma unroll
        for (int r = 0; r < 4; ++r) {
            float pre0 = acc0[r] + bias0;          // i (lo) | f (hi)
            float pre1 = acc1[r] + bias1;          // g (lo) | o (hi)
            float alt0 = __shfl_xor(pre0, 8);
            float alt1 = __shfl_xor(pre1, 8);
            if (lo) {
                float ig = sigmoidf_(pre0);
                float fg = sigmoidf_(alt0);
                float gg = tanhf_(pre1);
                float og = sigmoidf_(alt1);
                float c  = fg * creg[r] + ig * gg;
                creg[r]  = c;
                float h  = og * tanhf_(c);
                int m = wave * 16 + quad * 4 + r;
                hout[m * DIM + hb + u] = f2bf(h);
                if (layer) {
                    out[(size_t)t * BD + m * DIM + hb + u] = h;
                    if (t == T_STEPS - 1) {
                        out[(size_t)T_STEPS * BD + 1 * BD + m * DIM + hb + u] = h;  // hn[1]
                        out[(size_t)T_STEPS * BD + 3 * BD + m * DIM + hb + u] = c;  // cn[1]
                    }
                } else if (t == T_STEPS - 1) {
                    out[(size_t)T_STEPS * BD + 0 * BD + m * DIM + hb + u] = h;      // hn[0]
                    out[(size_t)T_STEPS * BD + 2 * BD + m * DIM + hb + u] = c;      // cn[0]
                }
            }
        }

        bar_arrive(myflag, (unsigned)(t + 1));
    }
}

extern "C" void kernel_launch(void* const* d_in, const int* in_sizes, int n_in,
                              void* d_out, int out_size, void* d_ws, size_t ws_size,
                              hipStream_t stream) {
    const float* x     = (const float*)d_in[0];
    const float* hx    = (const float*)d_in[1];
    const float* cx    = (const float*)d_in[2];
    const float* w_ih0 = (const float*)d_in[3];
    const float* w_hh0 = (const float*)d_in[4];
    const float* b_ih0 = (const float*)d_in[5];
    const float* b_hh0 = (const float*)d_in[6];
    const float* w_ih1 = (const float*)d_in[7];
    const float* w_hh1 = (const float*)d_in[8];
    const float* b_ih1 = (const float*)d_in[9];
    const float* b_hh1 = (const float*)d_in[10];
    float* outp = (float*)d_out;
    unsigned short* wsp = (unsigned short*)d_ws;

    void* args[] = { &x, &hx, &cx, &w_ih0, &w_hh0, &b_ih0, &b_hh0,
                     &w_ih1, &w_hh1, &b_ih1, &b_hh1, &outp, &wsp };
    hipLaunchCooperativeKernel((void*)lstm_fused, dim3(256), dim3(256),
                               args, 0, stream);
}

// Round 4
// 8989.309 us; speedup vs baseline: 2.2595x; 1.7090x over previous
//
#include <hip/hip_runtime.h>
#include <hip/hip_bf16.h>
#include <hip/hip_cooperative_groups.h>
#include <cstddef>

namespace cg = cooperative_groups;

typedef short bf16x8 __attribute__((ext_vector_type(8)));
typedef float f32x4 __attribute__((ext_vector_type(4)));

#define T_STEPS 512
#define BATCH   64
#define DIM     1024   // I == H == 1024
#define BD      (BATCH*DIM)      // 65536
#define XB_ELEMS ((size_t)T_STEPS*BATCH*DIM)  // 33554432
#define FLAG_STRIDE 16           // uints -> 64B between flags (own cache line)

__device__ __forceinline__ float sigmoidf_(float x) {
    return 1.f / (1.f + __expf(-x));
}
__device__ __forceinline__ float tanhf_(float x) {
    return 2.f / (1.f + __expf(-2.f * x)) - 1.f;
}
__device__ __forceinline__ unsigned short f2bf(float f) {
    union { float f; unsigned int u; } v; v.f = f;
    unsigned int u = v.u + 0x7fffu + ((v.u >> 16) & 1u);  // RNE
    return (unsigned short)(u >> 16);
}

// coherent (agent-scope, L1/L2-bypassing) 8B primitives for h traffic
__device__ __forceinline__ unsigned long long coh_load8(const void* p) {
    return __hip_atomic_load((const unsigned long long*)p,
                             __ATOMIC_RELAXED, __HIP_MEMORY_SCOPE_AGENT);
}
__device__ __forceinline__ void coh_store8(void* p, unsigned long long v) {
    __hip_atomic_store((unsigned long long*)p, v,
                       __ATOMIC_RELAXED, __HIP_MEMORY_SCOPE_AGENT);
}

// Grid: 256 blocks x 256 threads. Blocks 0..127 -> layer 0, 128..255 -> layer 1.
__global__ void __launch_bounds__(256, 1)
lstm_fused(const float* __restrict__ x,
           const float* __restrict__ hx,
           const float* __restrict__ cx,
           const float* __restrict__ w_ih0, const float* __restrict__ w_hh0,
           const float* __restrict__ b_ih0, const float* __restrict__ b_hh0,
           const float* __restrict__ w_ih1, const float* __restrict__ w_hh1,
           const float* __restrict__ b_ih1, const float* __restrict__ b_hh1,
           float* __restrict__ out,
           unsigned short* __restrict__ ws)
{
    // ws layout (bf16 elems): xb[T][B][DIM], h0[2][BD], h1[2][BD], flags
    unsigned short* xb = ws;
    unsigned short* h0 = ws + XB_ELEMS;
    unsigned short* h1 = h0 + 2 * BD;
    unsigned* flag0 = (unsigned*)(h1 + 2 * BD);        // [128 * FLAG_STRIDE]
    unsigned* flag1 = flag0 + 128 * FLAG_STRIDE;       // [128 * FLAG_STRIDE]

    const int tid   = threadIdx.x;
    const int lane  = tid & 63;
    const int wave  = tid >> 6;
    const int bid   = blockIdx.x;
    const int layer = bid >> 7;
    const int ib    = bid & 127;
    const int hb    = ib * 8;          // first hidden unit owned by this block

    // B operand in MFMA fragment order: [g(2)][ntile(2)][kchunk(32)][lane(64)][8]
    __shared__ __align__(16) unsigned short wB[65536];     // 128 KB
    __shared__ __align__(16) unsigned short hstage[64][8]; // 1 KB repack tile

    // ---- stage weight slices into LDS (one-time), fragment layout ----
    {
        const float* wsrcI = layer ? w_ih1 : w_ih0;
        const float* wsrcH = layer ? w_hh1 : w_hh0;
        for (int idx = tid; idx < 8192; idx += 256) {   // 8192 fragments of 8
            int l  = idx & 63;
            int kc = (idx >> 6) & 31;
            int n  = (idx >> 11) & 1;
            int g  = idx >> 12;
            int c  = l & 15, kq = l >> 4;
            int gate = n * 2 + (c >> 3);                // 0:i 1:f 2:g 3:o
            const float* wm = g ? wsrcH : wsrcI;
            const float* src = wm + (size_t)(gate * DIM + hb + (c & 7)) * DIM + kc * 32 + kq * 8;
            float4 v0 = *(const float4*)(src);
            float4 v1 = *(const float4*)(src + 4);
            unsigned short o[8];
            o[0] = f2bf(v0.x); o[1] = f2bf(v0.y); o[2] = f2bf(v0.z); o[3] = f2bf(v0.w);
            o[4] = f2bf(v1.x); o[5] = f2bf(v1.y); o[6] = f2bf(v1.z); o[7] = f2bf(v1.w);
            *(bf16x8*)(&wB[(size_t)idx * 8]) = *(const bf16x8*)o;
        }
    }

    // ---- cast x to bf16 into ws (grid-stride) ----
    {
        const int nthr = 256 * gridDim.x;
        const int gtid = bid * 256 + tid;
        const float4* xv = (const float4*)x;
        const int n4 = (int)(XB_ELEMS / 4);
        for (int i = gtid; i < n4; i += nthr) {
            float4 v = xv[i];
            ushort4 o;
            o.x = f2bf(v.x); o.y = f2bf(v.y); o.z = f2bf(v.z); o.w = f2bf(v.w);
            *(ushort4*)(xb + (size_t)i * 4) = o;
        }
    }

    // ---- init h ping-pong slot [1] from hx (used at t=0: (t-1)&1 == 1) ----
    {
        unsigned short* hdst = (layer ? h1 : h0) + BD;
        const float* hsrc = hx + (size_t)layer * BD;
        for (int e = tid; e < 512; e += 256) {
            int row = e >> 3, u = e & 7;
            hdst[row * DIM + hb + u] = f2bf(hsrc[row * DIM + hb + u]);
        }
    }

    // ---- zero own flag (every launch; deterministic under graph replay) ----
    if (tid == 0) {
        unsigned* f = (layer ? flag1 : flag0) + ib * FLAG_STRIDE;
        __hip_atomic_store(f, 0u, __ATOMIC_RELAXED, __HIP_MEMORY_SCOPE_AGENT);
    }

    const int col  = lane & 15;      // MFMA col within N-tile
    const int quad = lane >> 4;      // 0..3
    const bool lo  = col < 8;
    const int u    = lane & 7;       // hidden-unit offset for lo lanes

    // biases (per-lane, constant over time)
    const float* bi = layer ? b_ih1 : b_ih0;
    const float* bh = layer ? b_hh1 : b_hh0;
    const int r0 = (col < 8) ? (0 * DIM + hb + col) : (1 * DIM + hb + col - 8); // i|f
    const int r1 = (col < 8) ? (2 * DIM + hb + col) : (3 * DIM + hb + col - 8); // g|o
    const float bias0 = bi[r0] + bh[r0];
    const float bias1 = bi[r1] + bh[r1];

    // c-state in registers (lo lanes own 4 batch rows each)
    float creg[4];
    {
        const float* csrc = cx + (size_t)layer * BD;
        #pragma unroll
        for (int r = 0; r < 4; ++r) {
            int m = wave * 16 + quad * 4 + r;
            creg[r] = lo ? csrc[m * DIM + hb + u] : 0.f;
        }
    }

    cg::grid_group grid = cg::this_grid();
    __syncthreads();
    grid.sync();   // publishes xb, h init, zeroed flags (wbl2 + inv once)

    const int arow = wave * 16 + col;  // A-fragment row (batch index)

    // plain-load GEMM (xb path: L2-cacheable, stays warm — no invalidates ever)
    auto do_gemm_plain = [&](const unsigned short* Ap, int g, f32x4& a0v, f32x4& a1v) {
        const unsigned short* Abase = Ap + (size_t)arow * DIM + quad * 8;
        const unsigned short* B0 = &wB[(size_t)((g * 2 + 0) * 32) * 512 + lane * 8];
        const unsigned short* B1 = &wB[(size_t)((g * 2 + 1) * 32) * 512 + lane * 8];
        #pragma unroll 8
        for (int kc = 0; kc < 32; ++kc) {
            bf16x8 a  = *(const bf16x8*)(Abase + kc * 32);
            bf16x8 b0 = *(const bf16x8*)(B0 + (size_t)kc * 512);
            bf16x8 b1 = *(const bf16x8*)(B1 + (size_t)kc * 512);
            a0v = __builtin_amdgcn_mfma_f32_16x16x32_bf16(a, b0, a0v, 0, 0, 0);
            a1v = __builtin_amdgcn_mfma_f32_16x16x32_bf16(a, b1, a1v, 0, 0, 0);
        }
    };

    // coherent-load GEMM (h paths: device-written bf16, read straight from L3)
    auto do_gemm_coh = [&](const unsigned short* Ap, int g, f32x4& a0v, f32x4& a1v) {
        const unsigned short* Abase = Ap + (size_t)arow * DIM + quad * 8;
        const unsigned short* B0 = &wB[(size_t)((g * 2 + 0) * 32) * 512 + lane * 8];
        const unsigned short* B1 = &wB[(size_t)((g * 2 + 1) * 32) * 512 + lane * 8];
        #pragma unroll 8
        for (int kc = 0; kc < 32; ++kc) {
            union { bf16x8 v; unsigned long long q[2]; } au;
            au.q[0] = coh_load8(Abase + kc * 32);
            au.q[1] = coh_load8(Abase + kc * 32 + 4);
            bf16x8 b0 = *(const bf16x8*)(B0 + (size_t)kc * 512);
            bf16x8 b1 = *(const bf16x8*)(B1 + (size_t)kc * 512);
            a0v = __builtin_amdgcn_mfma_f32_16x16x32_bf16(au.v, b0, a0v, 0, 0, 0);
            a1v = __builtin_amdgcn_mfma_f32_16x16x32_bf16(au.v, b1, a1v, 0, 0, 0);
        }
    };

    // poll peers' flags; NO cache-maintenance fence (h reads are coherent loads)
    auto wait_all = [&](unsigned* flags, unsigned target) {
        if (tid < 128) {
            unsigned* f = flags + tid * FLAG_STRIDE;
            while (__hip_atomic_load(f, __ATOMIC_RELAXED, __HIP_MEMORY_SCOPE_AGENT) < target)
                __builtin_amdgcn_s_sleep(1);
        }
        __syncthreads();
    };

    unsigned* myflag = (layer ? flag1 : flag0) + ib * FLAG_STRIDE;

    for (int t = 0; t < T_STEPS; ++t) {
        f32x4 acc0 = {0.f, 0.f, 0.f, 0.f};
        f32x4 acc1 = {0.f, 0.f, 0.f, 0.f};

        if (!layer) {
            // input GEMM on static xb[t] — off the critical path
            do_gemm_plain(xb + (size_t)t * BD, 0, acc0, acc1);
            wait_all(flag0, (unsigned)t);                   // peers' h0[t-1] ready
            do_gemm_coh(h0 + (size_t)((t - 1) & 1) * BD, 1, acc0, acc1);
            if (t >= 2) wait_all(flag1, (unsigned)(t - 1)); // layer1 done reading slot
        } else {
            wait_all(flag1, (unsigned)t);                   // own h1[t-1] ready + slot free
            do_gemm_coh(h1 + (size_t)((t - 1) & 1) * BD, 1, acc0, acc1);
            wait_all(flag0, (unsigned)(t + 1));             // layer0's h0[t] ready
            do_gemm_coh(h0 + (size_t)(t & 1) * BD, 0, acc0, acc1);
        }

        unsigned short* hout = (layer ? h1 : h0) + (size_t)(t & 1) * BD;
        #pragma unroll
        for (int r = 0; r < 4; ++r) {
            float pre0 = acc0[r] + bias0;          // i (lo) | f (hi)
            float pre1 = acc1[r] + bias1;          // g (lo) | o (hi)
            float alt0 = __shfl_xor(pre0, 8);
            float alt1 = __shfl_xor(pre1, 8);
            if (lo) {
                float ig = sigmoidf_(pre0);
                float fg = sigmoidf_(alt0);
                float gg = tanhf_(pre1);
                float og = sigmoidf_(alt1);
                float c  = fg * creg[r] + ig * gg;
                creg[r]  = c;
                float h  = og * tanhf_(c);
                int m = wave * 16 + quad * 4 + r;
                hstage[m][u] = f2bf(h);
                if (layer) {
                    out[(size_t)t * BD + m * DIM + hb + u] = h;
                    if (t == T_STEPS - 1) {
                        out[(size_t)T_STEPS * BD + 1 * BD + m * DIM + hb + u] = h;  // hn[1]
                        out[(size_t)T_STEPS * BD + 3 * BD + m * DIM + hb + u] = c;  // cn[1]
                    }
                } else if (t == T_STEPS - 1) {
                    out[(size_t)T_STEPS * BD + 0 * BD + m * DIM + hb + u] = h;      // hn[0]
                    out[(size_t)T_STEPS * BD + 2 * BD + m * DIM + hb + u] = c;      // cn[0]
                }
            }
        }
        __syncthreads();                 // hstage complete
        if (tid < 64) {                  // 16B/row contiguous write-through
            const unsigned long long* src = (const unsigned long long*)&hstage[tid][0];
            unsigned long long v0 = src[0], v1 = src[1];
            void* dst = hout + (size_t)tid * DIM + hb;
            coh_store8(dst, v0);
            coh_store8((char*)dst + 8, v1);
        }
        asm volatile("s_waitcnt vmcnt(0)" ::: "memory");   // h at L3
        __syncthreads();                                   // all waves drained
        if (tid == 0)
            __hip_atomic_store(myflag, (unsigned)(t + 1),
                               __ATOMIC_RELAXED, __HIP_MEMORY_SCOPE_AGENT);
    }
}

extern "C" void kernel_launch(void* const* d_in, const int* in_sizes, int n_in,
                              void* d_out, int out_size, void* d_ws, size_t ws_size,
                              hipStream_t stream) {
    const float* x     = (const float*)d_in[0];
    const float* hx    = (const float*)d_in[1];
    const float* cx    = (const float*)d_in[2];
    const float* w_ih0 = (const float*)d_in[3];
    const float* w_hh0 = (const float*)d_in[4];
    const float* b_ih0 = (const float*)d_in[5];
    const float* b_hh0 = (const float*)d_in[6];
    const float* w_ih1 = (const float*)d_in[7];
    const float* w_hh1 = (const float*)d_in[8];
    const float* b_ih1 = (const float*)d_in[9];
    const float* b_hh1 = (const float*)d_in[10];
    float* outp = (float*)d_out;
    unsigned short* wsp = (unsigned short*)d_ws;

    void* args[] = { &x, &hx, &cx, &w_ih0, &w_hh0, &b_ih0, &b_hh0,
                     &w_ih1, &w_hh1, &b_ih1, &b_hh1, &outp, &wsp };
    hipLaunchCooperativeKernel((void*)lstm_fused, dim3(256), dim3(256),
                               args, 0, stream);
}